// Round 6
// baseline (72.075 us; speedup 1.0000x reference)
//
#include <hip/hip_runtime.h>
#include <hip/hip_fp16.h>
#include <math.h>

#define NV 10475
#define NDS 2048
#define NHAND 1554
#define NHA 777
#define NCONTACT 300
#define NQ (NHAND + NDS)             // 3602 query rows
#define NVEC4 (NV / 4)               // 2618 float4 per row
#define TAIL0 (NVEC4 * 4)            // 10472
#define MASK_DW ((NV + 31) / 32)     // 328

#define THREADS 1024                 // 16 waves: 8 queries x 2 waves each
#define QPB 8
#define BLOCKS ((NQ + QPB - 1) / QPB)  // 451

// dynamic LDS layout (bytes)
#define OFF_SXY  0
#define OFF_SZ   41904                   // NV*4=41900 -> pad16
#define OFF_CIDX (OFF_SZ + 20960)        // NV*2=20950 -> pad16   = 62864
#define OFF_PART (OFF_CIDX + 1200)       // 300*4                 = 64064
#define OFF_FLAG (OFF_PART + 128)        // 16 waves * {best,gb}  = 64192
#define SMEM_TOTAL (OFF_FLAG + 16)       //                       = 64208

#define GEO_THRESH 0.3f
#define EXT_THRESH 0.02f
#define A1c 0.04f
#define A2c 0.04f
#define B1c 0.07f
#define B2c 0.06f
#define C1c 0.01f
#define C2c 0.01f
#define D1c 0.023f
#define D2c 0.02f
#define CONTACT_W 0.5f
#define INSIDE_W 0.5f
#define HAND_W 1.0f

__device__ __forceinline__ void upd(float g, float cx, float cy, float cz,
                                    float px, float py, float pz, float& best) {
    float dx = px - cx, dy = py - cy, dz = pz - cz;
    float d2 = fmaf(dx, dx, fmaf(dy, dy, dz * dz));
    best = fminf(best, (g < GEO_THRESH) ? INFINITY : d2);
}

// ---------------------------------------------------------------------------
// Fused kernel: per-block LDS staging of fp16-rounded vertices; each query
// row is scanned by TWO waves (even/odd float4 chunks) for 2x memory-level
// parallelism; gdi gathered post-scan from the L2-hot row; last block to
// finish performs the masked-mean finalize (stream-k pattern, agent-scope
// release/acquire for cross-XCD visibility).
// ---------------------------------------------------------------------------
__global__ __launch_bounds__(THREADS, 8)
void fused_kernel(const float* __restrict__ verts,
                  const float* __restrict__ geodist,
                  const int* __restrict__ hand_idx,
                  const int* __restrict__ ds,
                  const int* __restrict__ cidx,
                  const float* __restrict__ hw,
                  float* __restrict__ hand_min,
                  float* __restrict__ ds_min,
                  float* __restrict__ gdiq,
                  int* __restrict__ done,
                  float* __restrict__ out) {
    extern __shared__ __align__(16) char smem[];
    __half2* sxy = (__half2*)(smem + OFF_SXY);
    __half*  sz  = (__half*)(smem + OFF_SZ);
    int* cidxs   = (int*)(smem + OFF_CIDX);
    float* part  = (float*)(smem + OFF_PART);
    int* lflag   = (int*)(smem + OFF_FLAG);

    const int tid = threadIdx.x;
    const int lane = tid & 63;
    const int wave = tid >> 6;

    // stage fp16-rounded vertices + contact index list into LDS
    for (int n = tid; n < NV; n += THREADS) {
        sxy[n] = __halves2half2(__float2half(verts[3 * n + 0]),
                                __float2half(verts[3 * n + 1]));
        sz[n] = __float2half(verts[3 * n + 2]);
    }
    if (tid < NCONTACT) cidxs[tid] = cidx[tid];
    __syncthreads();

    const int qslot = wave >> 1;        // 0..7
    const int sub = wave & 1;           // which half of the row
    const int gq = blockIdx.x * QPB + qslot;

    if (gq < NQ) {
        const bool is_ds = (gq >= NHAND);
        const int q = is_ds ? ds[gq - NHAND] : hand_idx[gq];
        const float* __restrict__ grow = geodist + (size_t)q * NV;

        const float2 pxy = __half22float2(sxy[q]);
        const float px = pxy.x, py = pxy.y;
        const float pz = __half2float(sz[q]);

        const float4* __restrict__ g4p = (const float4*)grow;  // 4B-align OK
        const uint4* __restrict__ sxy4 = (const uint4*)sxy;
        const uint2* __restrict__ sz2 = (const uint2*)sz;

        float best = INFINITY, gb = INFINITY;

        #pragma unroll 2
        for (int j = sub * 64 + lane; j < NVEC4; j += 128) {
            const float4 g4 = g4p[j];
            const uint4 xy = sxy4[j];
            const uint2 zz = sz2[j];
            const float2 c0 = __half22float2(*(const __half2*)&xy.x);
            const float2 c1 = __half22float2(*(const __half2*)&xy.y);
            const float2 c2 = __half22float2(*(const __half2*)&xy.z);
            const float2 c3 = __half22float2(*(const __half2*)&xy.w);
            const float2 z01 = __half22float2(*(const __half2*)&zz.x);
            const float2 z23 = __half22float2(*(const __half2*)&zz.y);
            upd(g4.x, c0.x, c0.y, z01.x, px, py, pz, best);
            upd(g4.y, c1.x, c1.y, z01.y, px, py, pz, best);
            upd(g4.z, c2.x, c2.y, z23.x, px, py, pz, best);
            upd(g4.w, c3.x, c3.y, z23.y, px, py, pz, best);
        }
        if (sub == 0 && lane < NV - TAIL0) {   // 3 tail candidates
            const int n = TAIL0 + lane;
            const float2 c = __half22float2(sxy[n]);
            upd(grow[n], c.x, c.y, __half2float(sz[n]), px, py, pz, best);
        }
        if (is_ds) {   // gdi: gather 300 contact columns from the L2-hot row
            for (int k = sub * 64 + lane; k < NCONTACT; k += 128)
                gb = fminf(gb, grow[cidxs[k]]);
        }

        #pragma unroll
        for (int off = 32; off > 0; off >>= 1) {
            best = fminf(best, __shfl_down(best, off));
            gb = fminf(gb, __shfl_down(gb, off));
        }
        if (lane == 0) { part[wave * 2] = best; part[wave * 2 + 1] = gb; }
    }
    __syncthreads();

    // combine wave pairs, write per-query outputs
    if (tid < QPB) {
        const int gq2 = blockIdx.x * QPB + tid;
        if (gq2 < NQ) {
            const float best = fminf(part[(2 * tid) * 2], part[(2 * tid + 1) * 2]);
            const float gb = fminf(part[(2 * tid) * 2 + 1], part[(2 * tid + 1) * 2 + 1]);
            const float d = sqrtf(best + 1e-12f);
            if (gq2 >= NHAND) {
                ds_min[gq2 - NHAND] = d;
                gdiq[gq2 - NHAND] = gb;
            } else {
                hand_min[gq2] = d;
            }
        }
    }

    // ---- last-block election ----
    if (tid == 0) {
        __threadfence();  // release our outputs device-wide (L2 writeback)
        const int old = __hip_atomic_fetch_add(done, 1, __ATOMIC_ACQ_REL,
                                               __HIP_MEMORY_SCOPE_AGENT);
        *lflag = (old == (int)gridDim.x - 1) ? 1 : 0;
    }
    __syncthreads();
    if (!*lflag) return;
    __builtin_amdgcn_fence(__ATOMIC_ACQUIRE, "agent");  // invalidate L1/L2

    // ---- finalize (this block only); reuse LDS over the sxy region ----
    unsigned int* imask = (unsigned int*)smem;           // 1312 B
    float (*red)[12] = (float (*)[12])(smem + 4096);     // 768 B

    for (int i = tid; i < MASK_DW; i += THREADS) imask[i] = 0u;
    __syncthreads();
    for (int i = tid; i < NDS; i += THREADS) {
        if (!(ds_min[i] > EXT_THRESH)) {
            const int v = ds[i];
            atomicOr(&imask[v >> 5], 1u << (v & 31));
        }
    }
    __syncthreads();

    float acc[12];
    #pragma unroll
    for (int k = 0; k < 12; ++k) acc[k] = 0.0f;

    for (int i = tid; i < NDS; i += THREADS) {
        const float m = ds_min[i];
        const int v = ds[i];
        const bool ins = (imask[v >> 5] >> (v & 31)) & 1u;
        if (!ins) {
            const float w = 1.0f / (5.0f * gdiq[i] + 1.0f);
            acc[0] += A1c * w * tanhf(m / A2c);
            acc[1] += 1.0f;
        } else {
            acc[2] += B1c * tanhf(m / B2c);
            acc[3] += 1.0f;
        }
    }
    for (int h = tid; h < NHAND; h += THREADS) {
        const float m = hand_min[h];
        const int v = hand_idx[h];
        const bool ins = (imask[v >> 5] >> (v & 31)) & 1u;
        const float w = -0.1f * hw[h] + 1.0f;
        const float o = w * C1c * tanhf(m / C2c);
        const float ii = D1c * tanhf(m / D2c);
        if (h < NHA) {
            if (!ins) { acc[4] += o;  acc[5] += 1.0f; }
            else      { acc[8] += ii; acc[9] += 1.0f; }
        } else {
            if (!ins) { acc[6]  += o;  acc[7]  += 1.0f; }
            else      { acc[10] += ii; acc[11] += 1.0f; }
        }
    }

    #pragma unroll
    for (int k = 0; k < 12; ++k) {
        float v = acc[k];
        #pragma unroll
        for (int off = 32; off > 0; off >>= 1)
            v += __shfl_down(v, off);
        acc[k] = v;
    }
    if (lane == 0) {
        #pragma unroll
        for (int k = 0; k < 12; ++k) red[wave][k] = acc[k];
    }
    __syncthreads();
    if (tid == 0) {
        float t[12];
        #pragma unroll
        for (int k = 0; k < 12; ++k) {
            float s = red[0][k];
            for (int w = 1; w < 16; ++w) s += red[w][k];
            t[k] = s;
        }
        const float contactloss = CONTACT_W * (t[0] / fmaxf(t[1], 1.0f));
        const float insideloss  = INSIDE_W  * (t[2] / fmaxf(t[3], 1.0f));
        const float hand_out = t[4] / fmaxf(t[5], 1.0f) + t[6]  / fmaxf(t[7], 1.0f);
        const float hand_in  = t[8] / fmaxf(t[9], 1.0f) + t[10] / fmaxf(t[11], 1.0f);
        out[0] = contactloss + insideloss + HAND_W * (hand_out + hand_in);
    }
}

extern "C" void kernel_launch(void* const* d_in, const int* in_sizes, int n_in,
                              void* d_out, int out_size, void* d_ws, size_t ws_size,
                              hipStream_t stream) {
    const float* vertices = (const float*)d_in[0];  // [1,NV,3]
    const float* geodist  = (const float*)d_in[1];  // [NV,NV]
    const float* hand_w   = (const float*)d_in[2];  // [NHAND]
    const int*   ds       = (const int*)d_in[3];    // [NDS]
    const int*   hand_idx = (const int*)d_in[4];    // [NHAND]
    const int*   cidx     = (const int*)d_in[5];    // [NCONTACT]
    float* out = (float*)d_out;

    char* p = (char*)d_ws;
    float* hand_min = (float*)p;  p += ((NHAND * 4 + 15) & ~15);
    float* ds_min = (float*)p;    p += ((NDS * 4 + 15) & ~15);
    float* gdiq = (float*)p;      p += ((NDS * 4 + 15) & ~15);
    int* done = (int*)p;          p += 16;

    // d_ws is poisoned 0xAA before timing -> counter must be zeroed each call
    hipMemsetAsync(done, 0, sizeof(int), stream);

    fused_kernel<<<BLOCKS, THREADS, SMEM_TOTAL, stream>>>(
        vertices, geodist, hand_idx, ds, cidx, hand_w,
        hand_min, ds_min, gdiq, done, out);
}